// Round 2
// baseline (13005.490 us; speedup 1.0000x reference)
//
#include <hip/hip_runtime.h>
#include <math.h>

// Problem dims: B=8, NS=32, L=128, H=768, LH=256, C=4
// N_SEQ = 256 word sequences, gate width 1024.

__device__ __forceinline__ float sigmoidf_(float x) { return 1.0f / (1.0f + expf(-x)); }

// v_add with DPP-shuffled self (VALU-pipe cross-lane reduce)
#define DPP_ADD(v, ctrl) ((v) + __int_as_float(__builtin_amdgcn_update_dpp( \
        0, __float_as_int(v), (ctrl), 0xF, 0xF, false)))
// quad_perm [1,0,3,2]=0xB1, [2,3,0,1]=0x4E, row_ror:4=0x124, row_ror:8=0x128

#define WS_PITCH 132   // k-major weight pitch (132%32==4 -> even bank spread)
#define AS_PITCH 20    // k-major h-tile pitch (20*k mod 32 spreads over quads)

// ---------------------------------------------------------------------------
__global__ void zero_f4(float4* __restrict__ p, int n) {
    int i = blockIdx.x * 256 + threadIdx.x;
    if (i < n) p[i] = make_float4(0.f, 0.f, 0.f, 0.f);
}

// ---------------------------------------------------------------------------
// Input-projection GEMM: Out[m][j] = sum_k A[m][k]*W[j][k] + b[j].
// N=2048 split fwd/bwd at 1024. tmajor=1 permutes out rows m=seq*128+t -> t*256+seq.
__global__ __launch_bounds__(256) void gemm_proj(
    const float* __restrict__ A, int M, int K,
    const float* __restrict__ Wf, const float* __restrict__ Wb,
    const float* __restrict__ bf, const float* __restrict__ bb,
    float* __restrict__ Of, float* __restrict__ Ob, int tmajor)
{
    __shared__ float As[16][132];
    __shared__ float Bs[16][132];
    const int t = threadIdx.x;
    const int n0 = blockIdx.x * 128;
    const int m0 = blockIdx.y * 128;
    const int sel = (n0 >= 1024);
    const float* Wp = sel ? Wb : Wf;
    const float* bp = sel ? bb : bf;
    float* Op = sel ? Ob : Of;
    const int n0d = n0 & 1023;

    const int tm = t >> 4;
    const int tn = t & 15;

    float acc[8][8];
#pragma unroll
    for (int i = 0; i < 8; i++)
#pragma unroll
        for (int j = 0; j < 8; j++) acc[i][j] = 0.f;

    for (int k0 = 0; k0 < K; k0 += 16) {
        __syncthreads();
#pragma unroll
        for (int rr = 0; rr < 2; rr++) {
            int idx = t + rr * 256;
            int row = idx >> 2, kq = idx & 3;
            float4 v = *(const float4*)&A[(size_t)(m0 + row) * K + k0 + kq * 4];
            As[kq * 4 + 0][row] = v.x; As[kq * 4 + 1][row] = v.y;
            As[kq * 4 + 2][row] = v.z; As[kq * 4 + 3][row] = v.w;
        }
#pragma unroll
        for (int rr = 0; rr < 2; rr++) {
            int idx = t + rr * 256;
            int row = idx >> 2, kq = idx & 3;
            float4 v = *(const float4*)&Wp[(size_t)(n0d + row) * K + k0 + kq * 4];
            Bs[kq * 4 + 0][row] = v.x; Bs[kq * 4 + 1][row] = v.y;
            Bs[kq * 4 + 2][row] = v.z; Bs[kq * 4 + 3][row] = v.w;
        }
        __syncthreads();
#pragma unroll
        for (int k = 0; k < 16; k++) {
            float4 a0 = *(const float4*)&As[k][tm * 4];
            float4 a1 = *(const float4*)&As[k][tm * 4 + 64];
            float4 b0 = *(const float4*)&Bs[k][tn * 4];
            float4 b1 = *(const float4*)&Bs[k][tn * 4 + 64];
            float av[8] = {a0.x, a0.y, a0.z, a0.w, a1.x, a1.y, a1.z, a1.w};
            float bv[8] = {b0.x, b0.y, b0.z, b0.w, b1.x, b1.y, b1.z, b1.w};
#pragma unroll
            for (int i = 0; i < 8; i++)
#pragma unroll
                for (int j = 0; j < 8; j++)
                    acc[i][j] += av[i] * bv[j];
        }
    }

#pragma unroll
    for (int ih = 0; ih < 2; ih++) {
#pragma unroll
        for (int i = 0; i < 4; i++) {
            int m = m0 + ih * 64 + tm * 4 + i;
            size_t mrow = tmajor ? (size_t)((m & 127) * 256 + (m >> 7)) : (size_t)m;
#pragma unroll
            for (int jh = 0; jh < 2; jh++) {
                int col = n0d + jh * 64 + tn * 4;
                float4 bias4 = *(const float4*)&bp[col];
                float4 r;
                r.x = acc[ih * 4 + i][jh * 4 + 0] + bias4.x;
                r.y = acc[ih * 4 + i][jh * 4 + 1] + bias4.y;
                r.z = acc[ih * 4 + i][jh * 4 + 2] + bias4.z;
                r.w = acc[ih * 4 + i][jh * 4 + 3] + bias4.w;
                *(float4*)&Op[mrow * 1024 + col] = r;
            }
        }
    }
}

// ---------------------------------------------------------------------------
// Persistent word-level BiLSTM: 256 WGs (dir x 16 seq-tiles x 8 unit-tiles),
// all 128 timesteps in one cooperative launch. Weights LDS-resident (k-major).
// 8-WG groups (same dir+seq-tile) sync via device-scope atomic barrier.
// Per thread: 8 gate-rows x 16 seqs, 16-way K-split over lanes, DPP reduce.
__global__ void __launch_bounds__(256, 1) word_lstm(
    const float* __restrict__ Gf, const float* __restrict__ Gb,
    const float* __restrict__ Whf, const float* __restrict__ Whb,
    const int* __restrict__ mask,
    float* __restrict__ h_ping, float* __restrict__ h_pong,
    float* __restrict__ pooled, int* __restrict__ bar)
{
    extern __shared__ float lds[];
    float* Ws = lds;                    // [256][132] k-major weights
    float* As = lds + 256 * WS_PITCH;   // [256][20] k-major h tile; Gex overlays

    const int tid = threadIdx.x;
    const int bid = blockIdx.x;
    const int ut  = bid >> 5;          // 0..7 unit tile (group members span XCDs evenly)
    const int rem = bid & 31;          // group id = (dir,seq-tile)
    const int dir = rem >> 4;
    const int st  = rem & 15;
    const int n0  = st * 16;
    const int u0  = ut * 32;
    const float* W = dir ? Whb : Whf;
    const float* G = dir ? Gb : Gf;
    const int hbase = dir * 65536;

    // ---- stage weights k-major, once ----
    {
        const int r_lo = tid & 63;
        const int kh = tid >> 6;                    // wave-uniform
        for (int rr = 0; rr < 2; rr++) {
            int r = r_lo + rr * 64;                 // 0..127 local gate row
            int jr = ((r >> 5) << 8) + u0 + (r & 31);
            const float* wp = W + (size_t)jr * 256 + kh * 4;
            for (int kq = 0; kq < 16; kq++) {
                float4 v = *(const float4*)(wp + kq * 16);
                int k = kq * 16 + kh * 4;
                Ws[(k + 0) * WS_PITCH + r] = v.x;
                Ws[(k + 1) * WS_PITCH + r] = v.y;
                Ws[(k + 2) * WS_PITCH + r] = v.z;
                Ws[(k + 3) * WS_PITCH + r] = v.w;
            }
        }
    }

    const int p  = tid & 15;        // k-slice lane (DPP rows = 16 lanes align with p)
    const int mg = tid >> 4;        // 0..15 -> rows mg*8..mg*8+7
    const int r0 = mg * 8;
    const int eu = tid & 31;        // epilogue: unit
    const int es = tid >> 5;        // epilogue: seq pair (2*es, 2*es+1)
    const int sseq = tid >> 4;      // staging: seq
    const int skl  = tid & 15;      // staging: k-low

    float c0 = 0.f, c1 = 0.f, ps0 = 0.f, ps1 = 0.f;
    int cnt0 = 0, cnt1 = 0;

    const float* hin = h_ping;
    float* hout = h_pong;

    __syncthreads();   // weights ready

#pragma unroll 1
    for (int t = 0; t < 128; t++) {
        const int te = dir ? (127 - t) : t;

        // stage h -> As k-major (k-low concurrent across lanes => 2-way banks)
        {
            const float* hp = hin + hbase + (n0 + sseq) * 256;
            float hv[16];
#pragma unroll
            for (int i = 0; i < 16; i++) hv[i] = hp[i * 16 + skl];
#pragma unroll
            for (int i = 0; i < 16; i++) As[(i * 16 + skl) * AS_PITCH + sseq] = hv[i];
        }
        // prefetch gates + mask for epilogue (independent of this step's GEMM)
        float gpre[8]; int mk0, mk1;
        {
            const int n_a = n0 + es * 2;
            const float* Ga = G + ((size_t)te * 256 + n_a) * 1024 + u0 + eu;
            const float* Gc = Ga + 1024;
#pragma unroll
            for (int g = 0; g < 4; g++) { gpre[g] = Ga[g * 256]; gpre[4 + g] = Gc[g * 256]; }
            mk0 = mask[n_a * 128 + te];
            mk1 = mask[(n_a + 1) * 128 + te];
        }
        __syncthreads();

        // ---- GEMM: acc[8 rows][16 seqs], K-slice k = 16j+p ----
        float acc[8][16];
#pragma unroll
        for (int i = 0; i < 8; i++)
#pragma unroll
            for (int s = 0; s < 16; s++) acc[i][s] = 0.f;

#pragma unroll 4
        for (int j = 0; j < 16; j++) {
            int k = j * 16 + p;
            const float* ap = As + k * AS_PITCH;
            const float* wp = Ws + k * WS_PITCH + r0;
            float4 a0 = *(const float4*)(ap);
            float4 a1 = *(const float4*)(ap + 4);
            float4 a2 = *(const float4*)(ap + 8);
            float4 a3 = *(const float4*)(ap + 12);
            float4 w0 = *(const float4*)(wp);
            float4 w1 = *(const float4*)(wp + 4);
            float av[16] = {a0.x, a0.y, a0.z, a0.w, a1.x, a1.y, a1.z, a1.w,
                            a2.x, a2.y, a2.z, a2.w, a3.x, a3.y, a3.z, a3.w};
            float wv[8] = {w0.x, w0.y, w0.z, w0.w, w1.x, w1.y, w1.z, w1.w};
#pragma unroll
            for (int i = 0; i < 8; i++)
#pragma unroll
                for (int s = 0; s < 16; s++)
                    acc[i][s] += wv[i] * av[s];
        }

        // ---- 16-way DPP reduce over p (VALU pipe); lanes p<4 end valid ----
#pragma unroll
        for (int i = 0; i < 8; i++)
#pragma unroll
            for (int s = 0; s < 16; s++) {
                float v = acc[i][s];
                v = DPP_ADD(v, 0xB1);
                v = DPP_ADD(v, 0x4E);
                v = DPP_ADD(v, 0x124);
                v = DPP_ADD(v, 0x128);
                acc[i][s] = v;
            }

        __syncthreads();             // As reads done -> Gex overlay safe
        if (p < 4) {                 // lane p writes seqs 4p..4p+3
            float* gex = As;
#pragma unroll
            for (int i = 0; i < 8; i++) {
                float4 v = make_float4(acc[i][4 * p], acc[i][4 * p + 1],
                                       acc[i][4 * p + 2], acc[i][4 * p + 3]);
                *(float4*)&gex[(r0 + i) * AS_PITCH + 4 * p] = v;
            }
        }
        __syncthreads();

        // ---- epilogue: 2 cells (unit eu, seqs 2es, 2es+1) ----
        {
            const float* gex = As;
            const int n_a = n0 + es * 2;
            {
                float iv = gex[(eu) * AS_PITCH + 2 * es] + gpre[0];
                float fv = gex[(32 + eu) * AS_PITCH + 2 * es] + gpre[1];
                float gv = gex[(64 + eu) * AS_PITCH + 2 * es] + gpre[2];
                float ov = gex[(96 + eu) * AS_PITCH + 2 * es] + gpre[3];
                c0 = sigmoidf_(fv) * c0 + sigmoidf_(iv) * tanhf(gv);
                float hn = sigmoidf_(ov) * tanhf(c0);
                hout[hbase + n_a * 256 + u0 + eu] = hn;
                if (mk0) { ps0 += hn; cnt0++; }
            }
            {
                float iv = gex[(eu) * AS_PITCH + 2 * es + 1] + gpre[4];
                float fv = gex[(32 + eu) * AS_PITCH + 2 * es + 1] + gpre[5];
                float gv = gex[(64 + eu) * AS_PITCH + 2 * es + 1] + gpre[6];
                float ov = gex[(96 + eu) * AS_PITCH + 2 * es + 1] + gpre[7];
                c1 = sigmoidf_(fv) * c1 + sigmoidf_(iv) * tanhf(gv);
                float hn = sigmoidf_(ov) * tanhf(c1);
                hout[hbase + (n_a + 1) * 256 + u0 + eu] = hn;
                if (mk1) { ps1 += hn; cnt1++; }
            }
        }

        { const float* tmp = hin; hin = hout; hout = (float*)tmp; }

        if (t < 127) {   // group barrier: 8 WGs sharing (dir,st)
            __threadfence();
            __syncthreads();
            if (tid == 0) {
                atomicAdd(&bar[rem], 1);
                const int target = 8 * (t + 1);
                while (__hip_atomic_load(&bar[rem], __ATOMIC_RELAXED,
                                         __HIP_MEMORY_SCOPE_AGENT) < target)
                    __builtin_amdgcn_s_sleep(2);
            }
            __syncthreads();
            __threadfence();
        }
    }

    // masked mean write (cnt==0 -> sum==0 -> writes 0)
    {
        const int n_a = n0 + es * 2;
        pooled[n_a * 512 + dir * 256 + u0 + eu]       = ps0 / fmaxf((float)cnt0, 1.0f);
        pooled[(n_a + 1) * 512 + dir * 256 + u0 + eu] = ps1 / fmaxf((float)cnt1, 1.0f);
    }
}

// ---------------------------------------------------------------------------
// Persistent sentence-level BiLSTM: 128 WGs (8 unit-tiles x [dir x 8 batch]),
// 32 steps, 16 groups of 8 WGs.
__global__ void __launch_bounds__(256, 1) sent_lstm(
    const float* __restrict__ Gsf, const float* __restrict__ Gsb,
    const float* __restrict__ Whf, const float* __restrict__ Whb,
    float* __restrict__ hs_ping, float* __restrict__ hs_pong,
    float* __restrict__ finalh, int* __restrict__ bar)
{
    extern __shared__ float lds[];
    float* Ws = lds;                 // [256][132]
    float* hs = lds + 256 * WS_PITCH; // [256]
    float* gex = hs + 256;            // [128]

    const int tid = threadIdx.x;
    const int bid = blockIdx.x;
    const int ut  = bid >> 4;
    const int grp = bid & 15;
    const int dir = grp >> 3;
    const int b   = grp & 7;
    const int u0  = ut * 32;
    const float* W = dir ? Whb : Whf;
    const float* G = dir ? Gsb : Gsf;

    {
        const int r_lo = tid & 63;
        const int kh = tid >> 6;
        for (int rr = 0; rr < 2; rr++) {
            int r = r_lo + rr * 64;
            int jr = ((r >> 5) << 8) + u0 + (r & 31);
            const float* wp = W + (size_t)jr * 256 + kh * 4;
            for (int kq = 0; kq < 16; kq++) {
                float4 v = *(const float4*)(wp + kq * 16);
                int k = kq * 16 + kh * 4;
                Ws[(k + 0) * WS_PITCH + r] = v.x;
                Ws[(k + 1) * WS_PITCH + r] = v.y;
                Ws[(k + 2) * WS_PITCH + r] = v.z;
                Ws[(k + 3) * WS_PITCH + r] = v.w;
            }
        }
    }

    const int p  = tid & 15;
    const int rg = tid >> 4;      // 0..15 -> rows rg*8..rg*8+7
    const int r0 = rg * 8;
    float c_r = 0.f;

    const float* hin = hs_ping;
    float* hout = hs_pong;

    __syncthreads();

#pragma unroll 1
    for (int t = 0; t < 32; t++) {
        const int te = dir ? (31 - t) : t;
        if (tid < 64) {
            float4 v = *(const float4*)&hin[dir * 2048 + b * 256 + tid * 4];
            *(float4*)&hs[tid * 4] = v;
        }
        __syncthreads();

        float acc[8];
#pragma unroll
        for (int i = 0; i < 8; i++) acc[i] = 0.f;
#pragma unroll 4
        for (int j = 0; j < 16; j++) {
            int k = j * 16 + p;
            float hk = hs[k];
            const float* wp = Ws + k * WS_PITCH + r0;
            float4 w0 = *(const float4*)(wp);
            float4 w1 = *(const float4*)(wp + 4);
            acc[0] += w0.x * hk; acc[1] += w0.y * hk;
            acc[2] += w0.z * hk; acc[3] += w0.w * hk;
            acc[4] += w1.x * hk; acc[5] += w1.y * hk;
            acc[6] += w1.z * hk; acc[7] += w1.w * hk;
        }
#pragma unroll
        for (int i = 0; i < 8; i++) {
            float v = acc[i];
            v = DPP_ADD(v, 0xB1);
            v = DPP_ADD(v, 0x4E);
            v = DPP_ADD(v, 0x124);
            v = DPP_ADD(v, 0x128);
            acc[i] = v;
        }
        __syncthreads();
        if (p == 0) {
            *(float4*)&gex[r0]     = make_float4(acc[0], acc[1], acc[2], acc[3]);
            *(float4*)&gex[r0 + 4] = make_float4(acc[4], acc[5], acc[6], acc[7]);
        }
        __syncthreads();

        if (tid < 32) {
            size_t gb = ((size_t)(b * 32 + te)) * 1024 + u0 + tid;
            float iv = gex[tid]      + G[gb];
            float fv = gex[32 + tid] + G[gb + 256];
            float gv = gex[64 + tid] + G[gb + 512];
            float ov = gex[96 + tid] + G[gb + 768];
            c_r = sigmoidf_(fv) * c_r + sigmoidf_(iv) * tanhf(gv);
            float hn = sigmoidf_(ov) * tanhf(c_r);
            hout[dir * 2048 + b * 256 + u0 + tid] = hn;
            if (te == 31) finalh[b * 512 + dir * 256 + u0 + tid] = hn;
        }
        { const float* tmp = hin; hin = hout; hout = (float*)tmp; }

        if (t < 31) {
            __threadfence();
            __syncthreads();
            if (tid == 0) {
                atomicAdd(&bar[grp], 1);
                const int target = 8 * (t + 1);
                while (__hip_atomic_load(&bar[grp], __ATOMIC_RELAXED,
                                         __HIP_MEMORY_SCOPE_AGENT) < target)
                    __builtin_amdgcn_s_sleep(2);
            }
            __syncthreads();
            __threadfence();
        }
    }
}

// ---------------------------------------------------------------------------
__global__ __launch_bounds__(256) void logits_k(const float* __restrict__ fh,
                                                const float* __restrict__ cw,
                                                const float* __restrict__ cb,
                                                float* __restrict__ out) {
    __shared__ float red[256];
    int tid = threadIdx.x;
    int o = tid >> 3;
    int b = o >> 2; int c = o & 3;
    int pp = tid & 7;
    float acc = 0.f;
    const float* fv = fh + b * 512 + pp * 64;
    const float* wv = cw + c * 512 + pp * 64;
#pragma unroll 8
    for (int e = 0; e < 64; e++) acc += fv[e] * wv[e];
    red[tid] = acc;
    __syncthreads();
    if (pp == 0) {
        float s = 0.f;
#pragma unroll
        for (int q = 0; q < 8; q++) s += red[o * 8 + q];
        out[o] = s + cb[c];
    }
}

// ---------------------------------------------------------------------------
extern "C" void kernel_launch(void* const* d_in, const int* in_sizes, int n_in,
                              void* d_out, int out_size, void* d_ws, size_t ws_size,
                              hipStream_t stream) {
    const float* X       = (const float*)d_in[0];
    const int*   mask    = (const int*)d_in[1];
    const float* wl_ih_f = (const float*)d_in[2];
    const float* wl_hh_f = (const float*)d_in[3];
    const float* wl_b_f  = (const float*)d_in[4];
    const float* wl_ih_b = (const float*)d_in[5];
    const float* wl_hh_b = (const float*)d_in[6];
    const float* wl_b_b  = (const float*)d_in[7];
    const float* ws_ih_f = (const float*)d_in[8];
    const float* ws_hh_f = (const float*)d_in[9];
    const float* ws_b_f  = (const float*)d_in[10];
    const float* ws_ih_b = (const float*)d_in[11];
    const float* ws_hh_b = (const float*)d_in[12];
    const float* ws_b_b  = (const float*)d_in[13];
    const float* cls_w   = (const float*)d_in[14];
    const float* cls_b   = (const float*)d_in[15];
    float* out = (float*)d_out;
    float* w = (float*)d_ws;
    (void)in_sizes; (void)n_in; (void)out_size; (void)ws_size;

    // workspace layout (floats)
    float* Gf      = w;                     // 128 MB, t-major [t][n][1024]
    float* Gb      = Gf + 33554432;
    float* Gsf     = Gb + 33554432;         // [b*32+t][1024]
    float* Gsb     = Gsf + 262144;
    float* pooled  = Gsb + 262144;          // [n][512]
    float* finalh  = pooled + 131072;       // [8][512]
    float* h_ping  = finalh + 4096;         // [dir][n][256] (zeroed)
    float* h_pong  = h_ping + 131072;
    float* hs_ping = h_pong + 131072;       // [dir][b][256] (zeroed)
    float* hs_pong = hs_ping + 4096;
    int*   barW    = (int*)(hs_pong + 4096);  // 32 (zeroed)
    int*   barS    = barW + 32;               // 16 (zeroed)

    // zero h_ping..barS = 270384 floats = 67596 float4
    zero_f4<<<265, 256, 0, stream>>>((float4*)h_ping, 67596);

    // word input projection (t-major output)
    gemm_proj<<<dim3(16, 256), 256, 0, stream>>>(X, 32768, 768,
        wl_ih_f, wl_ih_b, wl_b_f, wl_b_b, Gf, Gb, 1);

    // persistent word recurrence (cooperative, 256 WGs, 155648 B dyn LDS)
    {
        hipFuncSetAttribute((const void*)word_lstm,
                            hipFuncAttributeMaxDynamicSharedMemorySize, 155648);
        const float* a0 = Gf; const float* a1 = Gb;
        const float* a2 = wl_hh_f; const float* a3 = wl_hh_b;
        const int* a4 = mask;
        float* a5 = h_ping; float* a6 = h_pong; float* a7 = pooled;
        int* a8 = barW;
        void* args[] = {&a0, &a1, &a2, &a3, &a4, &a5, &a6, &a7, &a8};
        hipLaunchCooperativeKernel((const void*)word_lstm, dim3(256), dim3(256),
                                   args, 155648, stream);
    }

    // sentence input projection
    gemm_proj<<<dim3(16, 2), 256, 0, stream>>>(pooled, 256, 512,
        ws_ih_f, ws_ih_b, ws_b_f, ws_b_b, Gsf, Gsb, 0);

    // persistent sentence recurrence (cooperative, 128 WGs, 136704 B dyn LDS)
    {
        hipFuncSetAttribute((const void*)sent_lstm,
                            hipFuncAttributeMaxDynamicSharedMemorySize, 136704);
        const float* a0 = Gsf; const float* a1 = Gsb;
        const float* a2 = ws_hh_f; const float* a3 = ws_hh_b;
        float* a4 = hs_ping; float* a5 = hs_pong; float* a6 = finalh;
        int* a7 = barS;
        void* args[] = {&a0, &a1, &a2, &a3, &a4, &a5, &a6, &a7};
        hipLaunchCooperativeKernel((const void*)sent_lstm, dim3(128), dim3(256),
                                   args, 136704, stream);
    }

    logits_k<<<1, 256, 0, stream>>>(finalh, cls_w, cls_b, out);
}

// Round 3
// 1719.592 us; speedup vs baseline: 7.5631x; 7.5631x over previous
//
#include <hip/hip_runtime.h>
#include <math.h>

// Dims: B=8, NS=32, L=128, H=768, LH=256, C=4. N_SEQ=256, gates=1024.

typedef __bf16 bf16x8 __attribute__((ext_vector_type(8)));
typedef float  f32x4  __attribute__((ext_vector_type(4)));

__device__ __forceinline__ float sigmoidf_(float x){ return 1.0f/(1.0f+expf(-x)); }
__device__ __forceinline__ unsigned short f2bf(float x){
    unsigned int b = __float_as_uint(x);
    b += 0x7FFFu + ((b>>16)&1u);
    return (unsigned short)(b>>16);
}
__device__ __forceinline__ float bf2f(unsigned short h){
    return __uint_as_float(((unsigned int)h)<<16);
}
__device__ __forceinline__ void split_bf(float x, unsigned short &hi, unsigned short &lo){
    hi = f2bf(x);
    lo = f2bf(x - bf2f(hi));
}
__device__ __forceinline__ uint4 pack8(const unsigned short* s){
    uint4 u;
    u.x = (unsigned)s[0] | ((unsigned)s[1]<<16);
    u.y = (unsigned)s[2] | ((unsigned)s[3]<<16);
    u.z = (unsigned)s[4] | ((unsigned)s[5]<<16);
    u.w = (unsigned)s[6] | ((unsigned)s[7]<<16);
    return u;
}

// ---------------------------------------------------------------------------
__global__ void zero_f4(float4* __restrict__ p, int n) {
    int i = blockIdx.x * 256 + threadIdx.x;
    if (i < n) p[i] = make_float4(0.f, 0.f, 0.f, 0.f);
}

// ---------------------------------------------------------------------------
// Convert word W_ih (2 x [1024][768] fp32) -> bf16 hi/lo, flat same layout.
__global__ void prep_wih(const float* __restrict__ Wf, const float* __restrict__ Wb,
                         unsigned short* __restrict__ Whi, unsigned short* __restrict__ Wlo) {
    int idx = blockIdx.x * 256 + threadIdx.x;
    if (idx >= 1572864) return;
    int dir = idx / 786432;
    int r   = idx - dir * 786432;
    float v = (dir ? Wb : Wf)[r];
    unsigned short hi, lo; split_bf(v, hi, lo);
    Whi[idx] = hi; Wlo[idx] = lo;
}

// ---------------------------------------------------------------------------
// Build word W_hh LDS images: per (dir, u0t of 16 tiles):
//   [hi: 4g x 16u x 264][lo: same], 69632 B per image (pad to 68 KB for DMA).
// Gate-row source: row = g*256 + u0t*16 + u, k = 0..255.
__global__ void prep_whh(const float* __restrict__ Wf, const float* __restrict__ Wb,
                         unsigned short* __restrict__ Wimg) {
    int idx = blockIdx.x * 256 + threadIdx.x;
    if (idx >= 524288) return;
    int dir = idx >> 18;
    int r   = idx & 262143;
    int u0t = r >> 14;
    int g   = (r >> 12) & 3;
    int u   = (r >> 8) & 15;
    int k   = r & 255;
    const float* W = dir ? Wb : Wf;
    float v = W[(size_t)(g*256 + u0t*16 + u) * 256 + k];
    unsigned short hi, lo; split_bf(v, hi, lo);
    size_t base = (size_t)(dir*16 + u0t) * 34816;   // ushort elems per image
    Wimg[base + (g*16 + u)*264 + k]         = hi;
    Wimg[base + 16896 + (g*16 + u)*264 + k] = lo;
}

// ---------------------------------------------------------------------------
// transpose sentence-level W_hh (2 x [1024][256]) -> Wt[dir][k][j]
__global__ void transpose_whh(const float* __restrict__ Wf, const float* __restrict__ Wb,
                              float* __restrict__ Wt) {
    int idx = blockIdx.x * 256 + threadIdx.x;
    if (idx >= 524288) return;
    int dir = idx >> 18;
    int rem = idx & 262143;
    int k = rem >> 10;
    int j = rem & 1023;
    const float* Wp = dir ? Wb : Wf;
    Wt[idx] = Wp[j * 256 + k];
}

// ---------------------------------------------------------------------------
// Word input projection via split-bf16 MFMA (3-term):
//   G[t*256+n][j] = sum_k X[n*128+t][k] * Wih[j][k] + b[j]   (t-major output)
// BM=256 (4 waves x 64 rows), BN=128, BK=32. A converted fp32->hi/lo in-kernel;
// B pre-converted bf16. LDS pitch 40 elems (80 B: 16B-aligned frags, 2-way banks).
__global__ __launch_bounds__(256) void proj_mfma(
    const float* __restrict__ A,
    const unsigned short* __restrict__ Whi, const unsigned short* __restrict__ Wlo,
    const float* __restrict__ bfw, const float* __restrict__ bbw,
    float* __restrict__ Of, float* __restrict__ Ob)
{
    __shared__ unsigned short Ah[256*40];
    __shared__ unsigned short Al[256*40];
    __shared__ unsigned short Bh[128*40];
    __shared__ unsigned short Bl[128*40];
    const int tid = threadIdx.x;
    const int nt = blockIdx.x;        // 0..15
    const int mt = blockIdx.y;        // 0..127
    const int m0 = mt * 256;
    const int n0 = nt * 128;
    const int sel = (n0 >= 1024);
    const int n0d = n0 & 1023;
    const unsigned short* Bhp = Whi + (size_t)sel * 786432;
    const unsigned short* Blp = Wlo + (size_t)sel * 786432;
    const float* bias = sel ? bbw : bfw;
    float* Op = sel ? Ob : Of;
    const int wv = tid >> 6, ln = tid & 63;
    const int c = ln & 15, q = ln >> 4;

    f32x4 acc[4][8];
#pragma unroll
    for (int rb = 0; rb < 4; rb++)
#pragma unroll
        for (int cb = 0; cb < 8; cb++) acc[rb][cb] = f32x4{0.f,0.f,0.f,0.f};

    for (int k0 = 0; k0 < 768; k0 += 32) {
        __syncthreads();
        // A: 256 rows x 32 k fp32 -> hi/lo bf16 (512 segments of 16 elems)
#pragma unroll
        for (int it = 0; it < 2; it++) {
            int idx = tid + it * 256;
            int row = idx >> 1, kh = (idx & 1) * 16;
            const float* ap = A + (size_t)(m0 + row) * 768 + k0 + kh;
            unsigned short hi[16], lo[16];
#pragma unroll
            for (int e = 0; e < 16; e += 4) {
                float4 v = *(const float4*)(ap + e);
                split_bf(v.x, hi[e+0], lo[e+0]);
                split_bf(v.y, hi[e+1], lo[e+1]);
                split_bf(v.z, hi[e+2], lo[e+2]);
                split_bf(v.w, hi[e+3], lo[e+3]);
            }
            *(uint4*)&Ah[row*40 + kh]     = pack8(hi);
            *(uint4*)&Ah[row*40 + kh + 8] = pack8(hi + 8);
            *(uint4*)&Al[row*40 + kh]     = pack8(lo);
            *(uint4*)&Al[row*40 + kh + 8] = pack8(lo + 8);
        }
        // B: 128 rows x 32 k bf16 (512 chunks of 8)
#pragma unroll
        for (int it = 0; it < 2; it++) {
            int idx = tid + it * 256;
            int row = idx >> 2, kc = (idx & 3) * 8;
            *(uint4*)&Bh[row*40 + kc] = *(const uint4*)(Bhp + (size_t)(n0d + row)*768 + k0 + kc);
            *(uint4*)&Bl[row*40 + kc] = *(const uint4*)(Blp + (size_t)(n0d + row)*768 + k0 + kc);
        }
        __syncthreads();

        bf16x8 ah[4], al[4];
#pragma unroll
        for (int rb = 0; rb < 4; rb++) {
            ah[rb] = *(const bf16x8*)&Ah[(wv*64 + rb*16 + c)*40 + q*8];
            al[rb] = *(const bf16x8*)&Al[(wv*64 + rb*16 + c)*40 + q*8];
        }
#pragma unroll
        for (int cb = 0; cb < 8; cb++) {
            bf16x8 bh = *(const bf16x8*)&Bh[(cb*16 + c)*40 + q*8];
            bf16x8 bl = *(const bf16x8*)&Bl[(cb*16 + c)*40 + q*8];
#pragma unroll
            for (int rb = 0; rb < 4; rb++) {
                acc[rb][cb] = __builtin_amdgcn_mfma_f32_16x16x32_bf16(ah[rb], bh, acc[rb][cb], 0, 0, 0);
                acc[rb][cb] = __builtin_amdgcn_mfma_f32_16x16x32_bf16(ah[rb], bl, acc[rb][cb], 0, 0, 0);
                acc[rb][cb] = __builtin_amdgcn_mfma_f32_16x16x32_bf16(al[rb], bh, acc[rb][cb], 0, 0, 0);
            }
        }
    }

    // epilogue: C/D layout col=ln&15, row=q*4+reg; out row m -> (t=m&127, n=m>>7)
#pragma unroll
    for (int rb = 0; rb < 4; rb++) {
#pragma unroll
        for (int cb = 0; cb < 8; cb++) {
            int jcol = n0d + cb*16 + c;
            float bv = bias[jcol];
#pragma unroll
            for (int reg = 0; reg < 4; reg++) {
                int m = m0 + wv*64 + rb*16 + q*4 + reg;
                int tt = m & 127, nn = m >> 7;
                Op[(size_t)(tt*256 + nn)*1024 + jcol] = acc[rb][cb][reg] + bv;
            }
        }
    }
}

// ---------------------------------------------------------------------------
// One word-LSTM step via MFMA. Grid 256 = dir(2) x u0t(16) x nt(8).
// WG: 16 units x 4 gates x 32 seqs, K=256 in bf16 hi/lo (3-term MFMA).
// W image + h image staged via global_load_lds (16 B).
__global__ __launch_bounds__(256) void word_step_mfma(
    const float* __restrict__ Gf, const float* __restrict__ Gb,
    const unsigned short* __restrict__ Wimg,
    const unsigned short* __restrict__ hin_img,
    unsigned short* __restrict__ hout_img,
    const int* __restrict__ mask,
    float* __restrict__ c_st, float* __restrict__ pooled, int t)
{
    extern __shared__ char ldsbuf[];
    unsigned short* Wl = (unsigned short*)ldsbuf;            // 69632 B
    unsigned short* Hl = Wl + 34816;                         // 36864 B
    float* gex = (float*)(ldsbuf + 69632 + 36864);           // [4][16][36] fp32

    const int tid = threadIdx.x;
    const int bid = blockIdx.x;
    const int dir = bid >> 7;
    const int u0t = (bid >> 3) & 15;
    const int nt  = bid & 7;
    const int te  = dir ? (127 - t) : t;
    const float* G = dir ? Gb : Gf;

    const int wv = tid >> 6, ln = tid & 63;
    const int c = ln & 15, q = ln >> 4;

    // ---- async stage W image (68 chunks of 1 KB) + h image (36 chunks) ----
    {
        const char* wsrc = (const char*)(Wimg + (size_t)(dir*16 + u0t) * 34816);
        const char* hsrc = (const char*)(hin_img + (size_t)(dir*8 + nt) * 18432);
        char* wdst = (char*)Wl;
        char* hdst = (char*)Hl;
#pragma unroll
        for (int j = 0; j < 17; j++) {
            int i = wv + 4*j;
            __builtin_amdgcn_global_load_lds(
                (const __attribute__((address_space(1))) unsigned int*)(wsrc + i*1024 + ln*16),
                (__attribute__((address_space(3))) unsigned int*)(wdst + i*1024), 16, 0, 0);
        }
#pragma unroll
        for (int j = 0; j < 9; j++) {
            int i = wv + 4*j;
            __builtin_amdgcn_global_load_lds(
                (const __attribute__((address_space(1))) unsigned int*)(hsrc + i*1024 + ln*16),
                (__attribute__((address_space(3))) unsigned int*)(hdst + i*1024), 16, 0, 0);
        }
    }

    // ---- epilogue prefetch (independent of staged data) ----
    const int uu = tid & 15;          // unit within tile
    const int np = tid >> 4;          // seq-pair
    const int uglob = u0t*16 + uu;
    const int n_a = nt*32 + np*2;     // first of 2 seqs
    float gpre[8]; int mk0, mk1; float cold0, cold1;
    {
        const float* Ga = G + (size_t)(te*256 + n_a)*1024 + uglob;
        const float* Gc = Ga + 1024;
#pragma unroll
        for (int g = 0; g < 4; g++) { gpre[g] = Ga[g*256]; gpre[4+g] = Gc[g*256]; }
        mk0 = mask[n_a*128 + te];
        mk1 = mask[(n_a + 1)*128 + te];
        cold0 = c_st[dir*65536 + n_a*256 + uglob];
        cold1 = c_st[dir*65536 + (n_a + 1)*256 + uglob];
    }
    __syncthreads();   // waits vmcnt(0): staging complete

    // ---- MFMA: wave = gate wv; A rows = 16 units; B cols = 32 seqs (2 blocks) ----
    f32x4 acc[2];
    acc[0] = f32x4{0.f,0.f,0.f,0.f};
    acc[1] = f32x4{0.f,0.f,0.f,0.f};
#pragma unroll
    for (int kb = 0; kb < 8; kb++) {
        bf16x8 ahh = *(const bf16x8*)&Wl[(wv*16 + c)*264 + kb*32 + q*8];
        bf16x8 all_ = *(const bf16x8*)&Wl[16896 + (wv*16 + c)*264 + kb*32 + q*8];
#pragma unroll
        for (int sb = 0; sb < 2; sb++) {
            bf16x8 bh = *(const bf16x8*)&Hl[(sb*16 + c)*264 + kb*32 + q*8];
            bf16x8 bl = *(const bf16x8*)&Hl[8448 + (sb*16 + c)*264 + kb*32 + q*8];
            acc[sb] = __builtin_amdgcn_mfma_f32_16x16x32_bf16(ahh, bh, acc[sb], 0, 0, 0);
            acc[sb] = __builtin_amdgcn_mfma_f32_16x16x32_bf16(ahh, bl, acc[sb], 0, 0, 0);
            acc[sb] = __builtin_amdgcn_mfma_f32_16x16x32_bf16(all_, bh, acc[sb], 0, 0, 0);
        }
    }
    // write gates: row u=q*4+reg, col n=sb*16+c
#pragma unroll
    for (int sb = 0; sb < 2; sb++)
#pragma unroll
        for (int reg = 0; reg < 4; reg++)
            gex[(wv*16 + q*4 + reg)*36 + sb*16 + c] = acc[sb][reg];
    __syncthreads();

    // ---- cell update: thread handles (uu, n_a) and (uu, n_a+1) ----
    unsigned short* hout = hout_img + (size_t)(dir*8 + nt) * 18432;
    {
        int nl = np*2;
        float iv = gex[(0*16 + uu)*36 + nl] + gpre[0];
        float fv = gex[(1*16 + uu)*36 + nl] + gpre[1];
        float gv = gex[(2*16 + uu)*36 + nl] + gpre[2];
        float ov = gex[(3*16 + uu)*36 + nl] + gpre[3];
        float cn = sigmoidf_(fv)*cold0 + sigmoidf_(iv)*tanhf(gv);
        float hn = sigmoidf_(ov)*tanhf(cn);
        c_st[dir*65536 + n_a*256 + uglob] = cn;
        unsigned short hh, hl; split_bf(hn, hh, hl);
        hout[nl*264 + uglob] = hh;
        hout[8448 + nl*264 + uglob] = hl;
        if (mk0) pooled[n_a*512 + dir*256 + uglob] += hn;
    }
    {
        int nl = np*2 + 1;
        float iv = gex[(0*16 + uu)*36 + nl] + gpre[4];
        float fv = gex[(1*16 + uu)*36 + nl] + gpre[5];
        float gv = gex[(2*16 + uu)*36 + nl] + gpre[6];
        float ov = gex[(3*16 + uu)*36 + nl] + gpre[7];
        float cn = sigmoidf_(fv)*cold1 + sigmoidf_(iv)*tanhf(gv);
        float hn = sigmoidf_(ov)*tanhf(cn);
        c_st[dir*65536 + (n_a+1)*256 + uglob] = cn;
        unsigned short hh, hl; split_bf(hn, hh, hl);
        hout[nl*264 + uglob] = hh;
        hout[8448 + nl*264 + uglob] = hl;
        if (mk1) pooled[(n_a+1)*512 + dir*256 + uglob] += hn;
    }
}

// ---------------------------------------------------------------------------
// fp32 input-projection GEMM (sentence level): Out[m][j]=sum_k A[m][k]W[j][k]+b[j]
__global__ __launch_bounds__(256) void gemm_proj(
    const float* __restrict__ A, int M, int K,
    const float* __restrict__ Wf, const float* __restrict__ Wb,
    const float* __restrict__ bf, const float* __restrict__ bb,
    float* __restrict__ Of, float* __restrict__ Ob)
{
    __shared__ float As[16][132];
    __shared__ float Bs[16][132];
    const int t = threadIdx.x;
    const int n0 = blockIdx.x * 128;
    const int m0 = blockIdx.y * 128;
    const int sel = (n0 >= 1024);
    const float* Wp = sel ? Wb : Wf;
    const float* bp = sel ? bb : bf;
    float* Op = sel ? Ob : Of;
    const int n0d = n0 & 1023;
    const int tm = t >> 4;
    const int tn = t & 15;

    float acc[8][8];
#pragma unroll
    for (int i = 0; i < 8; i++)
#pragma unroll
        for (int j = 0; j < 8; j++) acc[i][j] = 0.f;

    for (int k0 = 0; k0 < K; k0 += 16) {
        __syncthreads();
#pragma unroll
        for (int rr = 0; rr < 2; rr++) {
            int idx = t + rr * 256;
            int row = idx >> 2, kq = idx & 3;
            float4 v = *(const float4*)&A[(size_t)(m0 + row) * K + k0 + kq * 4];
            As[kq*4+0][row] = v.x; As[kq*4+1][row] = v.y;
            As[kq*4+2][row] = v.z; As[kq*4+3][row] = v.w;
        }
#pragma unroll
        for (int rr = 0; rr < 2; rr++) {
            int idx = t + rr * 256;
            int row = idx >> 2, kq = idx & 3;
            float4 v = *(const float4*)&Wp[(size_t)(n0d + row) * K + k0 + kq * 4];
            Bs[kq*4+0][row] = v.x; Bs[kq*4+1][row] = v.y;
            Bs[kq*4+2][row] = v.z; Bs[kq*4+3][row] = v.w;
        }
        __syncthreads();
#pragma unroll
        for (int k = 0; k < 16; k++) {
            float4 a0 = *(const float4*)&As[k][tm*4];
            float4 a1 = *(const float4*)&As[k][tm*4+64];
            float4 b0 = *(const float4*)&Bs[k][tn*4];
            float4 b1 = *(const float4*)&Bs[k][tn*4+64];
            float av[8] = {a0.x,a0.y,a0.z,a0.w,a1.x,a1.y,a1.z,a1.w};
            float bv[8] = {b0.x,b0.y,b0.z,b0.w,b1.x,b1.y,b1.z,b1.w};
#pragma unroll
            for (int i = 0; i < 8; i++)
#pragma unroll
                for (int j = 0; j < 8; j++)
                    acc[i][j] += av[i] * bv[j];
        }
    }

#pragma unroll
    for (int ih = 0; ih < 2; ih++) {
#pragma unroll
        for (int i = 0; i < 4; i++) {
            int m = m0 + ih*64 + tm*4 + i;
#pragma unroll
            for (int jh = 0; jh < 2; jh++) {
                int col = n0d + jh*64 + tn*4;
                float4 bias4 = *(const float4*)&bp[col];
                float4 r;
                r.x = acc[ih*4+i][jh*4+0] + bias4.x;
                r.y = acc[ih*4+i][jh*4+1] + bias4.y;
                r.z = acc[ih*4+i][jh*4+2] + bias4.z;
                r.w = acc[ih*4+i][jh*4+3] + bias4.w;
                *(float4*)&Op[(size_t)m * 1024 + col] = r;
            }
        }
    }
}

// ---------------------------------------------------------------------------
__global__ __launch_bounds__(256) void pool_div(float* __restrict__ pooled,
                                                const int* __restrict__ mask) {
    __shared__ float red[256];
    int n = blockIdx.x, t = threadIdx.x;
    red[t] = (t < 128) ? (float)mask[n*128 + t] : 0.f;
    __syncthreads();
    for (int off = 128; off > 0; off >>= 1) {
        if (t < off) red[t] += red[t + off];
        __syncthreads();
    }
    float inv = 1.0f / fmaxf(red[0], 1.0f);
    pooled[n*512 + t] *= inv;
    pooled[n*512 + 256 + t] *= inv;
}

// ---------------------------------------------------------------------------
__global__ __launch_bounds__(256) void sent_step(
    const float* __restrict__ Gsf, const float* __restrict__ Gsb,
    const float* __restrict__ Wt,
    const float* __restrict__ h_in, float* __restrict__ h_out,
    float* __restrict__ c_s, float* __restrict__ final_h, int s)
{
    __shared__ float h_lds[256];
    __shared__ float part[256];
    __shared__ float ex[4][33];
    const int tid = threadIdx.x;
    const int bx = blockIdx.x;
    const int dir = bx >> 6;
    const int rb = bx & 63;
    const int b = rb >> 3;
    const int ut = rb & 7;
    const int u0 = ut * 32;
    const int t_eff = dir ? (31 - s) : s;
    const float* Gs = dir ? Gsb : Gsf;

    if (tid < 64) {
        float4 v = *(const float4*)&h_in[dir*2048 + b*256 + tid*4];
        *(float4*)&h_lds[tid*4] = v;
    }
    __syncthreads();

    const int kh = tid >> 7;
    const int rr = tid & 127;
    const int g = rr >> 5;
    const int uu = rr & 31;
    const int j = g*256 + u0 + uu;
    const float* wp = Wt + dir*262144 + kh*128*1024 + j;
    float acc = 0.f;
#pragma unroll 8
    for (int k = 0; k < 128; k++)
        acc += wp[k*1024] * h_lds[kh*128 + k];
    part[tid] = acc;
    __syncthreads();
    if (tid < 128) ex[g][uu] = part[tid] + part[tid + 128];
    __syncthreads();

    if (tid < 32) {
        int u = u0 + tid;
        size_t gb = (size_t)(b*32 + t_eff)*1024 + u;
        float iv = ex[0][tid] + Gs[gb];
        float fv = ex[1][tid] + Gs[gb + 256];
        float gv = ex[2][tid] + Gs[gb + 512];
        float ov = ex[3][tid] + Gs[gb + 768];
        int ci = dir*2048 + b*256 + u;
        float cold = c_s[ci];
        float cn = sigmoidf_(fv)*cold + sigmoidf_(iv)*tanhf(gv);
        float hn = sigmoidf_(ov)*tanhf(cn);
        c_s[ci] = cn;
        h_out[ci] = hn;
        if (t_eff == 31) final_h[b*512 + dir*256 + u] = hn;
    }
}

// ---------------------------------------------------------------------------
__global__ __launch_bounds__(256) void logits_k(const float* __restrict__ fh,
                                                const float* __restrict__ cw,
                                                const float* __restrict__ cb,
                                                float* __restrict__ out) {
    __shared__ float red[256];
    int tid = threadIdx.x;
    int o = tid >> 3;
    int b = o >> 2; int c = o & 3;
    int pp = tid & 7;
    float acc = 0.f;
    const float* fv = fh + b*512 + pp*64;
    const float* wv = cw + c*512 + pp*64;
#pragma unroll 8
    for (int e = 0; e < 64; e++) acc += fv[e]*wv[e];
    red[tid] = acc;
    __syncthreads();
    if (pp == 0) {
        float s = 0.f;
#pragma unroll
        for (int qq = 0; qq < 8; qq++) s += red[o*8 + qq];
        out[o] = s + cb[c];
    }
}

// ---------------------------------------------------------------------------
extern "C" void kernel_launch(void* const* d_in, const int* in_sizes, int n_in,
                              void* d_out, int out_size, void* d_ws, size_t ws_size,
                              hipStream_t stream) {
    const float* X       = (const float*)d_in[0];
    const int*   mask    = (const int*)d_in[1];
    const float* wl_ih_f = (const float*)d_in[2];
    const float* wl_hh_f = (const float*)d_in[3];
    const float* wl_b_f  = (const float*)d_in[4];
    const float* wl_ih_b = (const float*)d_in[5];
    const float* wl_hh_b = (const float*)d_in[6];
    const float* wl_b_b  = (const float*)d_in[7];
    const float* ws_ih_f = (const float*)d_in[8];
    const float* ws_hh_f = (const float*)d_in[9];
    const float* ws_b_f  = (const float*)d_in[10];
    const float* ws_ih_b = (const float*)d_in[11];
    const float* ws_hh_b = (const float*)d_in[12];
    const float* ws_b_b  = (const float*)d_in[13];
    const float* cls_w   = (const float*)d_in[14];
    const float* cls_b   = (const float*)d_in[15];
    float* out = (float*)d_out;
    float* w = (float*)d_ws;
    (void)in_sizes; (void)n_in; (void)out_size; (void)ws_size;

    // workspace layout (float offsets)
    float* Gf     = w;                         // 33,554,432  (t-major [t][n][1024])
    float* Gb     = Gf + 33554432;             // 33,554,432
    float* Gsf    = Gb + 33554432;             // 262,144
    float* Gsb    = Gsf + 262144;              // 262,144
    float* Wt     = Gsb + 262144;              // 524,288
    float* finalh = Wt + 524288;               // 4,096
    unsigned short* Wihhi = (unsigned short*)(finalh + 4096);     // 1,572,864 ushorts
    unsigned short* Wihlo = Wihhi + 1572864;                      // 1,572,864
    unsigned short* Wimg  = Wihlo + 1572864;                      // 1,114,112 ushorts
    // ---- zero region ----
    float* c_st   = (float*)(Wimg + 1114112);  // 131,072
    float* pooled = c_st + 131072;             // 131,072
    float* hs0    = pooled + 131072;           // 4,096
    float* hs1    = hs0 + 4096;                // 4,096
    float* cs     = hs1 + 4096;                // 4,096
    unsigned short* hA = (unsigned short*)(cs + 4096);  // 294,912 ushorts (16 x 36,864 B)
    unsigned short* hB = hA + 294912;                   // 294,912
    // zero floats: 131072*2 + 4096*3 + 147456*2 = 569,344 -> 142,336 float4

    zero_f4<<<556, 256, 0, stream>>>((float4*)c_st, 142336);
    prep_wih<<<6144, 256, 0, stream>>>(wl_ih_f, wl_ih_b, Wihhi, Wihlo);
    prep_whh<<<2048, 256, 0, stream>>>(wl_hh_f, wl_hh_b, Wimg);
    transpose_whh<<<2048, 256, 0, stream>>>(ws_hh_f, ws_hh_b, Wt);

    // word input projection (split-bf16 MFMA, t-major out)
    proj_mfma<<<dim3(16, 128), 256, 0, stream>>>(X, Wihhi, Wihlo,
                                                 wl_b_f, wl_b_b, Gf, Gb);

    // word recurrence: 128 per-step MFMA launches, h ping-pong in bf16 hi/lo images
    hipFuncSetAttribute((const void*)word_step_mfma,
                        hipFuncAttributeMaxDynamicSharedMemorySize, 115712);
    for (int t = 0; t < 128; t++) {
        const unsigned short* hin = (t & 1) ? hB : hA;
        unsigned short* hout      = (t & 1) ? hA : hB;
        word_step_mfma<<<256, 256, 115712, stream>>>(Gf, Gb, Wimg, hin, hout,
                                                     mask, c_st, pooled, t);
    }

    pool_div<<<256, 256, 0, stream>>>(pooled, mask);

    // sentence input projection (fp32): (256x512) @ (512x2048)
    gemm_proj<<<dim3(16, 2), 256, 0, stream>>>(pooled, 256, 512,
                                               ws_ih_f, ws_ih_b, ws_b_f, ws_b_b,
                                               Gsf, Gsb);

    for (int s = 0; s < 32; s++) {
        float* hin  = (s & 1) ? hs1 : hs0;
        float* hout = (s & 1) ? hs0 : hs1;
        sent_step<<<128, 256, 0, stream>>>(Gsf, Gsb, Wt, hin, hout, cs, finalh, s);
    }

    logits_k<<<1, 256, 0, stream>>>(finalh, cls_w, cls_b, out);
}